// Round 1
// baseline (423.108 us; speedup 1.0000x reference)
//
#include <hip/hip_runtime.h>

#define STEPS 32768
#define DIO 63
#define HSZ 256
#define NL 6
#define BM 128
#define THREADS 512

#define NBG   (NL * 768 * HSZ)   // packed i/g/o weights, bf16
#define NBIAS (NL * 768)         // fused b_ih + b_hh, f32
#define NBIN  (HSZ * 64)         // W_in padded K 63->64, bf16
#define NBFC  (64 * HSZ)         // W_fc padded N 63->64, bf16

typedef __bf16 bf16_8 __attribute__((ext_vector_type(8)));
typedef float f32x4 __attribute__((ext_vector_type(4)));

__device__ __forceinline__ unsigned short f2bf(float f) {
    unsigned int u = __float_as_uint(f);
    u = u + 0x7fffu + ((u >> 16) & 1u);   // round-to-nearest-even
    return (unsigned short)(u >> 16);
}

__device__ __forceinline__ float fsig(float x) {
    return __builtin_amdgcn_rcpf(1.f + __builtin_amdgcn_exp2f(x * -1.442695041f));
}
__device__ __forceinline__ float ftanh(float x) {
    return 2.f * __builtin_amdgcn_rcpf(1.f + __builtin_amdgcn_exp2f(x * -2.885390082f)) - 1.f;
}

// ---- weight preprocessing: fp32 -> bf16, pack i/g/o gate rows, fuse biases ----
__global__ void prep_kernel(const float* __restrict__ W_in,
                            const float* __restrict__ W_ih,
                            const float* __restrict__ b_ih,
                            const float* __restrict__ b_hh,
                            const float* __restrict__ W_fc,
                            unsigned short* __restrict__ Bg,
                            float* __restrict__ bias,
                            unsigned short* __restrict__ Bin,
                            unsigned short* __restrict__ Bfc) {
    int idx = blockIdx.x * 256 + threadIdx.x;
    if (idx < NBG) {
        // Bg[(l*768 + j)*256 + k] = W_ih[l][r(j)][k]; r: i->0..255, g->512..767, o->768..1023
        int k = idx & (HSZ - 1);
        int j = (idx >> 8) % 768;
        int l = idx / (768 * HSZ);
        int r = (j < 256) ? j : j + 256;
        Bg[idx] = f2bf(W_ih[(size_t)(l * 1024 + r) * HSZ + k]);
        return;
    }
    idx -= NBG;
    if (idx < NBIAS) {
        int j = idx % 768, l = idx / 768;
        int r = (j < 256) ? j : j + 256;
        bias[idx] = b_ih[l * 1024 + r] + b_hh[l * 1024 + r];
        return;
    }
    idx -= NBIAS;
    if (idx < NBIN) {
        int k = idx & 63, n = idx >> 6;
        Bin[idx] = (k < DIO) ? f2bf(W_in[n * DIO + k]) : (unsigned short)0;
        return;
    }
    idx -= NBIN;
    if (idx < NBFC) {
        int k = idx & (HSZ - 1), n = idx >> 8;
        Bfc[idx] = (n < DIO) ? f2bf(W_fc[n * HSZ + k]) : (unsigned short)0;
    }
}

// ---- fused MLP-ized LSTM: one block = 128 rows through all layers ----
__global__ __launch_bounds__(THREADS, 2) void rnn_fused(
    const float* __restrict__ inp, const float* __restrict__ b_in,
    const float* __restrict__ b_fc,
    const unsigned short* __restrict__ Bg, const float* __restrict__ bias,
    const unsigned short* __restrict__ Bin, const unsigned short* __restrict__ Bfc,
    float* __restrict__ out) {
    __shared__ __align__(16) unsigned short h_lds[BM * HSZ];   // 64KB, [row][col] bf16, XOR-swizzled
    __shared__ __align__(16) unsigned short in_lds[BM * 64];   // 16KB, [row][k] bf16, XOR-swizzled

    const int tid = threadIdx.x;
    const int lane = tid & 63;
    const int l15 = lane & 15;
    const int lq = lane >> 4;
    const int wid = tid >> 6;
    const int wr = wid >> 2;   // 0..1 (64-row slice)
    const int wc = wid & 3;    // 0..3 (64-col slice)
    const int row0 = blockIdx.x * BM;

    // ---- stage input tile (128 x 63 fp32 -> bf16, K padded to 64) ----
    for (int idx = tid; idx < BM * 64; idx += THREADS) {
        int r = idx >> 6, k = idx & 63;
        float v = (k < DIO) ? inp[(size_t)(row0 + r) * DIO + k] : 0.f;
        int off = (r * 128 + k * 2) ^ ((r & 7) << 4);
        *(unsigned short*)((char*)in_lds + off) = f2bf(v);
    }
    __syncthreads();

    // ---- input GEMM: x = inp @ W_in^T + b_in -> h_lds ----
    {
        f32x4 acc[4][4];
#pragma unroll
        for (int m = 0; m < 4; ++m)
#pragma unroll
            for (int n = 0; n < 4; ++n) acc[m][n] = (f32x4){0.f, 0.f, 0.f, 0.f};
#pragma unroll
        for (int kk = 0; kk < 2; ++kk) {
            bf16_8 a[4];
            int kb = kk * 64 + lq * 16;
#pragma unroll
            for (int m = 0; m < 4; ++m) {
                int row = wr * 64 + m * 16 + l15;
                a[m] = *(const bf16_8*)((const char*)in_lds + ((row * 128 + kb) ^ ((row & 7) << 4)));
            }
#pragma unroll
            for (int n = 0; n < 4; ++n) {
                int col = wc * 64 + n * 16 + l15;
                bf16_8 b = *(const bf16_8*)(Bin + col * 64 + kk * 32 + lq * 8);
#pragma unroll
                for (int m = 0; m < 4; ++m)
                    acc[m][n] = __builtin_amdgcn_mfma_f32_16x16x32_bf16(a[m], b, acc[m][n], 0, 0, 0);
            }
        }
#pragma unroll
        for (int n = 0; n < 4; ++n) {
            int col = wc * 64 + n * 16 + l15;
            float bn = b_in[col];
#pragma unroll
            for (int m = 0; m < 4; ++m) {
#pragma unroll
                for (int r = 0; r < 4; ++r) {
                    int row = wr * 64 + m * 16 + lq * 4 + r;  // C/D: col=lane&15, row=(lane>>4)*4+reg
                    *(unsigned short*)((char*)h_lds + ((row * 512 + col * 2) ^ ((row & 7) << 4))) =
                        f2bf(acc[m][n][r] + bn);
                }
            }
        }
    }
    __syncthreads();

    // ---- 6 layers: gates (i,g,o only; f is dead since c_prev==0) ----
    for (int l = 0; l < NL; ++l) {
        const unsigned short* Bl = Bg + (size_t)l * 768 * HSZ;
        const float* bl = bias + l * 768;
        f32x4 tt[4][4];
#pragma unroll
        for (int g = 0; g < 3; ++g) {
            f32x4 acc[4][4];
#pragma unroll
            for (int m = 0; m < 4; ++m)
#pragma unroll
                for (int n = 0; n < 4; ++n) acc[m][n] = (f32x4){0.f, 0.f, 0.f, 0.f};
            const unsigned short* Bp = Bl + g * 256 * HSZ;
#pragma unroll
            for (int kk = 0; kk < 8; ++kk) {
                bf16_8 a[4];
                int kb = kk * 64 + lq * 16;
#pragma unroll
                for (int m = 0; m < 4; ++m) {
                    int row = wr * 64 + m * 16 + l15;
                    a[m] = *(const bf16_8*)((const char*)h_lds + ((row * 512 + kb) ^ ((row & 7) << 4)));
                }
#pragma unroll
                for (int n = 0; n < 4; ++n) {
                    int col = wc * 64 + n * 16 + l15;
                    bf16_8 b = *(const bf16_8*)(Bp + col * HSZ + kk * 32 + lq * 8);
#pragma unroll
                    for (int m = 0; m < 4; ++m)
                        acc[m][n] = __builtin_amdgcn_mfma_f32_16x16x32_bf16(a[m], b, acc[m][n], 0, 0, 0);
                }
            }
            // activations: g0: tt=sig(i); g1: tt=tanh(sig(i)*tanh(g)); g2: tt=sig(o)*tanh(c)=h
#pragma unroll
            for (int n = 0; n < 4; ++n) {
                float bn = bl[g * 256 + wc * 64 + n * 16 + l15];
#pragma unroll
                for (int m = 0; m < 4; ++m) {
#pragma unroll
                    for (int r = 0; r < 4; ++r) {
                        float v = acc[m][n][r] + bn;
                        if (g == 0)      tt[m][n][r] = fsig(v);
                        else if (g == 1) tt[m][n][r] = ftanh(tt[m][n][r] * ftanh(v));
                        else             tt[m][n][r] = fsig(v) * tt[m][n][r];
                    }
                }
            }
        }
        __syncthreads();   // all waves done reading h_lds
#pragma unroll
        for (int n = 0; n < 4; ++n) {
            int col = wc * 64 + n * 16 + l15;
#pragma unroll
            for (int m = 0; m < 4; ++m) {
#pragma unroll
                for (int r = 0; r < 4; ++r) {
                    int row = wr * 64 + m * 16 + lq * 4 + r;
                    *(unsigned short*)((char*)h_lds + ((row * 512 + col * 2) ^ ((row & 7) << 4))) =
                        f2bf(tt[m][n][r]);
                }
            }
        }
        __syncthreads();
    }

    // ---- final GEMM: out = h @ W_fc^T + b_fc (N padded 63->64) ----
    {
        f32x4 o4[4];
#pragma unroll
        for (int n = 0; n < 4; ++n) o4[n] = (f32x4){0.f, 0.f, 0.f, 0.f};
#pragma unroll
        for (int kk = 0; kk < 8; ++kk) {
            int kb = kk * 64 + lq * 16;
            int arow = wid * 16 + l15;
            bf16_8 a = *(const bf16_8*)((const char*)h_lds + ((arow * 512 + kb) ^ ((arow & 7) << 4)));
#pragma unroll
            for (int n = 0; n < 4; ++n) {
                bf16_8 b = *(const bf16_8*)(Bfc + (n * 16 + l15) * HSZ + kk * 32 + lq * 8);
                o4[n] = __builtin_amdgcn_mfma_f32_16x16x32_bf16(a, b, o4[n], 0, 0, 0);
            }
        }
#pragma unroll
        for (int n = 0; n < 4; ++n) {
            int col = n * 16 + l15;
            if (col < DIO) {
                float bn = b_fc[col];
#pragma unroll
                for (int r = 0; r < 4; ++r) {
                    int row = wid * 16 + lq * 4 + r;
                    out[(size_t)(row0 + row) * DIO + col] = o4[n][r] + bn;
                }
            }
        }
    }
}

extern "C" void kernel_launch(void* const* d_in, const int* in_sizes, int n_in,
                              void* d_out, int out_size, void* d_ws, size_t ws_size,
                              hipStream_t stream) {
    const float* inputs = (const float*)d_in[0];
    const float* W_in   = (const float*)d_in[1];
    const float* b_in   = (const float*)d_in[2];
    const float* W_ih   = (const float*)d_in[3];
    // d_in[4] = W_hh: unused (h_prev == 0 every step)
    const float* b_ih   = (const float*)d_in[5];
    const float* b_hh   = (const float*)d_in[6];
    const float* W_fc   = (const float*)d_in[7];
    const float* b_fc   = (const float*)d_in[8];

    unsigned short* Bg  = (unsigned short*)d_ws;
    float* bias         = (float*)((char*)d_ws + (size_t)NBG * 2);
    unsigned short* Bin = (unsigned short*)((char*)bias + (size_t)NBIAS * 4);
    unsigned short* Bfc = Bin + NBIN;

    int total = NBG + NBIAS + NBIN + NBFC;
    prep_kernel<<<(total + 255) / 256, 256, 0, stream>>>(W_in, W_ih, b_ih, b_hh, W_fc,
                                                         Bg, bias, Bin, Bfc);
    rnn_fused<<<STEPS / BM, THREADS, 0, stream>>>(inputs, b_in, b_fc, Bg, bias, Bin, Bfc,
                                                  (float*)d_out);
}

// Round 2
// 366.151 us; speedup vs baseline: 1.1556x; 1.1556x over previous
//
#include <hip/hip_runtime.h>

#define STEPS 32768
#define DIO 63
#define HSZ 256
#define NL 6
#define BM 64
#define THREADS 512

// fragment-ordered weights in d_ws (see prep_kernel)
#define NBGF  (NL * 3 * 16 * 8 * 64 * 8)   // 1,179,648 bf16: [l][g][nb][kk][lane][e]
#define NBIAS (NL * 768)                    // fused b_ih+b_hh (i,g,o), f32
#define NBINF (16 * 2 * 64 * 8)             // 16,384 bf16: W_in  [nb][kk][lane][e], K padded to 64
#define NBFCF (4 * 8 * 64 * 8)              // 16,384 bf16: W_fc  [nb][kk][lane][e], N padded to 64

typedef __bf16 bf16_8 __attribute__((ext_vector_type(8)));
typedef float f32x4 __attribute__((ext_vector_type(4)));

#define LOG2E  1.4426950408889634f
#define LOG2E2 2.8853900817779268f

__device__ __forceinline__ unsigned short f2bf(float f) {
    unsigned int u = __float_as_uint(f);
    u = u + 0x7fffu + ((u >> 16) & 1u);   // RNE
    return (unsigned short)(u >> 16);
}

// ---- weight prep: fp32 -> bf16, MFMA-fragment order, coalesced per-wave chunks ----
// Fragment chunk (nb,kk) = 1KB contiguous: lane l holds B[col=nb*16+(l&15)][k=kk*32+(l>>4)*8 .. +8]
__global__ void prep_kernel(const float* __restrict__ W_in,
                            const float* __restrict__ W_ih,
                            const float* __restrict__ b_ih,
                            const float* __restrict__ b_hh,
                            const float* __restrict__ W_fc,
                            unsigned short* __restrict__ Bg,
                            float* __restrict__ bias,
                            unsigned short* __restrict__ Bin,
                            unsigned short* __restrict__ Bfc) {
    int idx = blockIdx.x * 256 + threadIdx.x;
    if (idx < NBGF) {
        int e    = idx & 7;
        int lane = (idx >> 3) & 63;
        int kk   = (idx >> 9) & 7;
        int nb   = (idx >> 12) & 15;
        int lg   = idx >> 16;          // 0..17
        int l = lg / 3, g = lg % 3;
        int col = nb * 16 + (lane & 15);
        int k   = kk * 32 + (lane >> 4) * 8 + e;
        int r   = col + (g == 0 ? 0 : (g == 1 ? 512 : 768));   // torch gate order i,f,g,o; f dead
        Bg[idx] = f2bf(W_ih[((size_t)l * 1024 + r) * HSZ + k]);
        return;
    }
    idx -= NBGF;
    if (idx < NBIAS) {
        int j = idx % 768, l = idx / 768;
        int r = (j < 256) ? j : j + 256;
        bias[idx] = b_ih[l * 1024 + r] + b_hh[l * 1024 + r];
        return;
    }
    idx -= NBIAS;
    if (idx < NBINF) {
        int e = idx & 7, lane = (idx >> 3) & 63, kk = (idx >> 9) & 1, nb = idx >> 10;
        int col = nb * 16 + (lane & 15);
        int k   = kk * 32 + (lane >> 4) * 8 + e;
        Bin[idx] = (k < DIO) ? f2bf(W_in[col * DIO + k]) : (unsigned short)0;
        return;
    }
    idx -= NBINF;
    if (idx < NBFCF) {
        int e = idx & 7, lane = (idx >> 3) & 63, kk = (idx >> 9) & 7, nb = idx >> 12;
        int col = nb * 16 + (lane & 15);
        int k   = kk * 32 + (lane >> 4) * 8 + e;
        Bfc[idx] = (col < DIO) ? f2bf(W_fc[col * HSZ + k]) : (unsigned short)0;
    }
}

// ---- fused MLP-ized LSTM: one block = 64 rows through all layers ----
// 8 waves, each owns all 64 rows x 32 cols (nb = wid*2 + n); no B duplication.
__global__ __launch_bounds__(THREADS, 4) void rnn_fused(
    const float* __restrict__ inp, const float* __restrict__ b_in,
    const float* __restrict__ b_fc,
    const unsigned short* __restrict__ Bg, const float* __restrict__ bias,
    const unsigned short* __restrict__ Bin, const unsigned short* __restrict__ Bfc,
    float* __restrict__ out) {
    __shared__ __align__(16) unsigned short h_lds[BM * HSZ];   // 32KB, row stride 512B, XOR-swizzled
    __shared__ __align__(16) unsigned short in_lds[BM * 64];   //  8KB, row stride 128B, XOR-swizzled

    const int tid = threadIdx.x;
    const int lane = tid & 63;
    const int l15 = lane & 15;
    const int lq = lane >> 4;
    const int wid = tid >> 6;
    const int row0 = blockIdx.x * BM;

    // ---- stage input tile (64 x 63 fp32 -> bf16, K padded to 64) ----
    for (int idx = tid; idx < BM * 64; idx += THREADS) {
        int r = idx >> 6, k = idx & 63;
        float v = (k < DIO) ? inp[(size_t)(row0 + r) * DIO + k] : 0.f;
        int off = (r * 128 + k * 2) ^ ((r & 7) << 4);
        *(__bf16*)((char*)in_lds + off) = (__bf16)v;
    }
    __syncthreads();

    // ---- input GEMM: x = inp @ W_in^T + b_in -> h_lds (no activation) ----
    {
        f32x4 acc[4][2];
#pragma unroll
        for (int m = 0; m < 4; ++m)
#pragma unroll
            for (int n = 0; n < 2; ++n) acc[m][n] = (f32x4){0.f, 0.f, 0.f, 0.f};
#pragma unroll
        for (int kk = 0; kk < 2; ++kk) {
            bf16_8 a[4];
#pragma unroll
            for (int m = 0; m < 4; ++m) {
                int row = m * 16 + l15;
                a[m] = *(const bf16_8*)((const char*)in_lds +
                        ((row * 128 + kk * 64 + lq * 16) ^ ((row & 7) << 4)));
            }
#pragma unroll
            for (int n = 0; n < 2; ++n) {
                int nb = wid * 2 + n;
                bf16_8 b = *(const bf16_8*)(Bin + ((nb * 2 + kk) << 9) + lane * 8);
#pragma unroll
                for (int m = 0; m < 4; ++m)
                    acc[m][n] = __builtin_amdgcn_mfma_f32_16x16x32_bf16(a[m], b, acc[m][n], 0, 0, 0);
            }
        }
#pragma unroll
        for (int n = 0; n < 2; ++n) {
            int col = wid * 32 + n * 16 + l15;
            float bn = b_in[col];
#pragma unroll
            for (int m = 0; m < 4; ++m)
#pragma unroll
                for (int r = 0; r < 4; ++r) {
                    int row = m * 16 + lq * 4 + r;   // C/D: col=lane&15, row=(lane>>4)*4+reg
                    *(__bf16*)((char*)h_lds + ((row * 512 + col * 2) ^ ((row & 7) << 4))) =
                        (__bf16)(acc[m][n][r] + bn);
                }
        }
    }
    __syncthreads();

    // ---- 6 layers: i,g,o gates only (f*c_prev == 0) ----
    for (int l = 0; l < NL; ++l) {
        const float* bl = bias + l * 768;
        f32x4 tt[4][2];
#pragma unroll
        for (int g = 0; g < 3; ++g) {
            const unsigned short* Bp = Bg + ((l * 3 + g) << 16);
            f32x4 acc[4][2];
#pragma unroll
            for (int m = 0; m < 4; ++m)
#pragma unroll
                for (int n = 0; n < 2; ++n) acc[m][n] = (f32x4){0.f, 0.f, 0.f, 0.f};
#pragma unroll
            for (int kk = 0; kk < 8; ++kk) {
                bf16_8 a[4];
#pragma unroll
                for (int m = 0; m < 4; ++m) {
                    int row = m * 16 + l15;
                    a[m] = *(const bf16_8*)((const char*)h_lds +
                            ((row * 512 + kk * 64 + lq * 16) ^ ((row & 7) << 4)));
                }
#pragma unroll
                for (int n = 0; n < 2; ++n) {
                    int nb = wid * 2 + n;
                    bf16_8 b = *(const bf16_8*)(Bp + ((nb * 8 + kk) << 9) + lane * 8);
#pragma unroll
                    for (int m = 0; m < 4; ++m)
                        acc[m][n] = __builtin_amdgcn_mfma_f32_16x16x32_bf16(a[m], b, acc[m][n], 0, 0, 0);
                }
            }
            // activations, in-register per gate:
            //  g0: tt = exp2(i*log2e)                      (ei)
            //  g1: c = sig(i)*tanh(g) via shared rcp; tt = tanh(c) via Pade(5,4)
            //  g2: h = tt * sig(o)
#pragma unroll
            for (int n = 0; n < 2; ++n) {
                float bn = bl[g * 256 + wid * 32 + n * 16 + l15];
#pragma unroll
                for (int m = 0; m < 4; ++m)
#pragma unroll
                    for (int r = 0; r < 4; ++r) {
                        float v = acc[m][n][r] + bn;
                        v = fminf(fmaxf(v, -15.f), 15.f);
                        if (g == 0) {
                            tt[m][n][r] = __builtin_amdgcn_exp2f(v * LOG2E);
                        } else if (g == 1) {
                            float eg = __builtin_amdgcn_exp2f(v * LOG2E2);
                            float ei = tt[m][n][r];
                            float c = ei * (eg - 1.f) *
                                      __builtin_amdgcn_rcpf((1.f + ei) * (1.f + eg));
                            float z = c * c;
                            float tn = fmaf(z + 105.f, z, 945.f);
                            float td = fmaf(fmaf(15.f, z, 420.f), z, 945.f);
                            tt[m][n][r] = c * tn * __builtin_amdgcn_rcpf(td);
                        } else {
                            float eo = __builtin_amdgcn_exp2f(v * LOG2E);
                            tt[m][n][r] = tt[m][n][r] * eo *
                                          __builtin_amdgcn_rcpf(1.f + eo);
                        }
                    }
            }
        }
        __syncthreads();   // all waves done reading h_lds
#pragma unroll
        for (int n = 0; n < 2; ++n) {
            int col = wid * 32 + n * 16 + l15;
#pragma unroll
            for (int m = 0; m < 4; ++m)
#pragma unroll
                for (int r = 0; r < 4; ++r) {
                    int row = m * 16 + lq * 4 + r;
                    *(__bf16*)((char*)h_lds + ((row * 512 + col * 2) ^ ((row & 7) << 4))) =
                        (__bf16)tt[m][n][r];
                }
        }
        __syncthreads();
    }

    // ---- final GEMM: out = h @ W_fc^T + b_fc (N padded 63->64) ----
    {
        const int mt = wid & 3;          // row tile
        const int nb0 = (wid >> 2) * 2;  // col tiles nb0, nb0+1
        f32x4 o4[2];
#pragma unroll
        for (int n = 0; n < 2; ++n) o4[n] = (f32x4){0.f, 0.f, 0.f, 0.f};
#pragma unroll
        for (int kk = 0; kk < 8; ++kk) {
            int row = mt * 16 + l15;
            bf16_8 a = *(const bf16_8*)((const char*)h_lds +
                        ((row * 512 + kk * 64 + lq * 16) ^ ((row & 7) << 4)));
#pragma unroll
            for (int n = 0; n < 2; ++n) {
                bf16_8 b = *(const bf16_8*)(Bfc + (((nb0 + n) * 8 + kk) << 9) + lane * 8);
                o4[n] = __builtin_amdgcn_mfma_f32_16x16x32_bf16(a, b, o4[n], 0, 0, 0);
            }
        }
#pragma unroll
        for (int n = 0; n < 2; ++n) {
            int col = (nb0 + n) * 16 + l15;
            if (col < DIO) {
                float bn = b_fc[col];
#pragma unroll
                for (int r = 0; r < 4; ++r) {
                    int row = mt * 16 + lq * 4 + r;
                    out[(size_t)(row0 + row) * DIO + col] = o4[n][r] + bn;
                }
            }
        }
    }
}

extern "C" void kernel_launch(void* const* d_in, const int* in_sizes, int n_in,
                              void* d_out, int out_size, void* d_ws, size_t ws_size,
                              hipStream_t stream) {
    const float* inputs = (const float*)d_in[0];
    const float* W_in   = (const float*)d_in[1];
    const float* b_in   = (const float*)d_in[2];
    const float* W_ih   = (const float*)d_in[3];
    // d_in[4] = W_hh: unused (h_prev == 0 every step)
    const float* b_ih   = (const float*)d_in[5];
    const float* b_hh   = (const float*)d_in[6];
    const float* W_fc   = (const float*)d_in[7];
    const float* b_fc   = (const float*)d_in[8];

    unsigned short* Bg  = (unsigned short*)d_ws;
    float* bias         = (float*)((char*)d_ws + (size_t)NBGF * 2);
    unsigned short* Bin = (unsigned short*)((char*)bias + (size_t)NBIAS * 4);
    unsigned short* Bfc = Bin + NBINF;

    int total = NBGF + NBIAS + NBINF + NBFCF;
    prep_kernel<<<(total + 255) / 256, 256, 0, stream>>>(W_in, W_ih, b_ih, b_hh, W_fc,
                                                         Bg, bias, Bin, Bfc);
    rnn_fused<<<STEPS / BM, THREADS, 0, stream>>>(inputs, b_in, b_fc, Bg, bias, Bin, Bfc,
                                                  (float*)d_out);
}

// Round 3
// 162.262 us; speedup vs baseline: 2.6076x; 2.2565x over previous
//
#include <hip/hip_runtime.h>

#define STEPS 32768
#define DIO 63
#define HSZ 256
#define NL 6
#define BM 64
#define THREADS 512

// fragment-ordered weights in d_ws (see prep_kernel)
#define NBGF  (NL * 3 * 16 * 8 * 64 * 8)   // 1,179,648 bf16: [l][g][nb][kk][lane][e]
#define NBIAS (NL * 768)                    // fused b_ih+b_hh (i,g,o), f32
#define NBINF (16 * 2 * 64 * 8)             // 16,384 bf16: W_in  [nb][kk][lane][e], K padded to 64
#define NBFCF (4 * 8 * 64 * 8)              // 16,384 bf16: W_fc  [nb][kk][lane][e], N padded to 64

typedef __bf16 bf16_8 __attribute__((ext_vector_type(8)));
typedef float f32x4 __attribute__((ext_vector_type(4)));

#define LOG2E  1.4426950408889634f
#define LOG2E2 2.8853900817779268f

__device__ __forceinline__ unsigned short f2bf(float f) {
    unsigned int u = __float_as_uint(f);
    u = u + 0x7fffu + ((u >> 16) & 1u);   // RNE
    return (unsigned short)(u >> 16);
}

// ---- weight prep: fp32 -> bf16, MFMA-fragment order, coalesced per-wave chunks ----
// Fragment chunk (nb,kk) = 1KB contiguous: lane l holds B[col=nb*16+(l&15)][k=kk*32+(l>>4)*8 .. +8]
__global__ void prep_kernel(const float* __restrict__ W_in,
                            const float* __restrict__ W_ih,
                            const float* __restrict__ b_ih,
                            const float* __restrict__ b_hh,
                            const float* __restrict__ W_fc,
                            unsigned short* __restrict__ Bg,
                            float* __restrict__ bias,
                            unsigned short* __restrict__ Bin,
                            unsigned short* __restrict__ Bfc) {
    int idx = blockIdx.x * 256 + threadIdx.x;
    if (idx < NBGF) {
        int e    = idx & 7;
        int lane = (idx >> 3) & 63;
        int kk   = (idx >> 9) & 7;
        int nb   = (idx >> 12) & 15;
        int lg   = idx >> 16;          // 0..17
        int l = lg / 3, g = lg % 3;
        int col = nb * 16 + (lane & 15);
        int k   = kk * 32 + (lane >> 4) * 8 + e;
        int r   = col + (g == 0 ? 0 : (g == 1 ? 512 : 768));   // torch gate order i,f,g,o; f dead
        Bg[idx] = f2bf(W_ih[((size_t)l * 1024 + r) * HSZ + k]);
        return;
    }
    idx -= NBGF;
    if (idx < NBIAS) {
        int j = idx % 768, l = idx / 768;
        int r = (j < 256) ? j : j + 256;
        bias[idx] = b_ih[l * 1024 + r] + b_hh[l * 1024 + r];
        return;
    }
    idx -= NBIAS;
    if (idx < NBINF) {
        int e = idx & 7, lane = (idx >> 3) & 63, kk = (idx >> 9) & 1, nb = idx >> 10;
        int col = nb * 16 + (lane & 15);
        int k   = kk * 32 + (lane >> 4) * 8 + e;
        Bin[idx] = (k < DIO) ? f2bf(W_in[col * DIO + k]) : (unsigned short)0;
        return;
    }
    idx -= NBINF;
    if (idx < NBFCF) {
        int e = idx & 7, lane = (idx >> 3) & 63, kk = (idx >> 9) & 7, nb = idx >> 12;
        int col = nb * 16 + (lane & 15);
        int k   = kk * 32 + (lane >> 4) * 8 + e;
        Bfc[idx] = (col < DIO) ? f2bf(W_fc[col * HSZ + k]) : (unsigned short)0;
    }
}

// ---- fused MLP-ized LSTM: one block = 64 rows through all layers ----
// 8 waves, each owns all 64 rows x 32 cols (nb = wid*2 + n); no B duplication.
// launch_bounds 2nd arg behaves as min BLOCKS/CU (measured R1/R2: (512,2)->128 VGPR,
// (512,4)->64 VGPR): 2 blocks * 8 waves = 16 waves/CU = 4 waves/SIMD -> 128 VGPR cap.
// Register demand ~110 -> fits, no scratch spills (R2's 830MB phantom WRITE_SIZE).
__global__ __launch_bounds__(THREADS, 2) void rnn_fused(
    const float* __restrict__ inp, const float* __restrict__ b_in,
    const float* __restrict__ b_fc,
    const unsigned short* __restrict__ Bg, const float* __restrict__ bias,
    const unsigned short* __restrict__ Bin, const unsigned short* __restrict__ Bfc,
    float* __restrict__ out) {
    __shared__ __align__(16) unsigned short h_lds[BM * HSZ];   // 32KB, row stride 512B, XOR-swizzled
    __shared__ __align__(16) unsigned short in_lds[BM * 64];   //  8KB, row stride 128B, XOR-swizzled

    const int tid = threadIdx.x;
    const int lane = tid & 63;
    const int l15 = lane & 15;
    const int lq = lane >> 4;
    const int wid = tid >> 6;
    const int row0 = blockIdx.x * BM;

    // ---- stage input tile (64 x 63 fp32 -> bf16, K padded to 64) ----
    for (int idx = tid; idx < BM * 64; idx += THREADS) {
        int r = idx >> 6, k = idx & 63;
        float v = (k < DIO) ? inp[(size_t)(row0 + r) * DIO + k] : 0.f;
        int off = (r * 128 + k * 2) ^ ((r & 7) << 4);
        *(__bf16*)((char*)in_lds + off) = (__bf16)v;
    }
    __syncthreads();

    // ---- input GEMM: x = inp @ W_in^T + b_in -> h_lds (no activation) ----
    {
        f32x4 acc[4][2];
#pragma unroll
        for (int m = 0; m < 4; ++m)
#pragma unroll
            for (int n = 0; n < 2; ++n) acc[m][n] = (f32x4){0.f, 0.f, 0.f, 0.f};
#pragma unroll
        for (int kk = 0; kk < 2; ++kk) {
            bf16_8 a[4];
#pragma unroll
            for (int m = 0; m < 4; ++m) {
                int row = m * 16 + l15;
                a[m] = *(const bf16_8*)((const char*)in_lds +
                        ((row * 128 + kk * 64 + lq * 16) ^ ((row & 7) << 4)));
            }
#pragma unroll
            for (int n = 0; n < 2; ++n) {
                int nb = wid * 2 + n;
                bf16_8 b = *(const bf16_8*)(Bin + ((nb * 2 + kk) << 9) + lane * 8);
#pragma unroll
                for (int m = 0; m < 4; ++m)
                    acc[m][n] = __builtin_amdgcn_mfma_f32_16x16x32_bf16(a[m], b, acc[m][n], 0, 0, 0);
            }
        }
#pragma unroll
        for (int n = 0; n < 2; ++n) {
            int col = wid * 32 + n * 16 + l15;
            float bn = b_in[col];
#pragma unroll
            for (int m = 0; m < 4; ++m)
#pragma unroll
                for (int r = 0; r < 4; ++r) {
                    int row = m * 16 + lq * 4 + r;   // C/D: col=lane&15, row=(lane>>4)*4+reg
                    *(__bf16*)((char*)h_lds + ((row * 512 + col * 2) ^ ((row & 7) << 4))) =
                        (__bf16)(acc[m][n][r] + bn);
                }
        }
    }
    __syncthreads();

    // ---- 6 layers: i,g,o gates only (f*c_prev == 0) ----
    for (int l = 0; l < NL; ++l) {
        const float* bl = bias + l * 768;
        f32x4 tt[4][2];
#pragma unroll
        for (int g = 0; g < 3; ++g) {
            const unsigned short* Bp = Bg + ((l * 3 + g) << 16);
            f32x4 acc[4][2];
#pragma unroll
            for (int m = 0; m < 4; ++m)
#pragma unroll
                for (int n = 0; n < 2; ++n) acc[m][n] = (f32x4){0.f, 0.f, 0.f, 0.f};
#pragma unroll
            for (int kk = 0; kk < 8; ++kk) {
                bf16_8 a[4];
#pragma unroll
                for (int m = 0; m < 4; ++m) {
                    int row = m * 16 + l15;
                    a[m] = *(const bf16_8*)((const char*)h_lds +
                            ((row * 512 + kk * 64 + lq * 16) ^ ((row & 7) << 4)));
                }
#pragma unroll
                for (int n = 0; n < 2; ++n) {
                    int nb = wid * 2 + n;
                    bf16_8 b = *(const bf16_8*)(Bp + ((nb * 8 + kk) << 9) + lane * 8);
#pragma unroll
                    for (int m = 0; m < 4; ++m)
                        acc[m][n] = __builtin_amdgcn_mfma_f32_16x16x32_bf16(a[m], b, acc[m][n], 0, 0, 0);
                }
            }
            // activations, in-register per gate:
            //  g0: tt = exp(i)
            //  g1: c = sig(i)*tanh(g) via shared rcp; tt = tanh(c) via Pade(5,4)
            //  g2: h = tt * sig(o)
#pragma unroll
            for (int n = 0; n < 2; ++n) {
                float bn = bl[g * 256 + wid * 32 + n * 16 + l15];
#pragma unroll
                for (int m = 0; m < 4; ++m)
#pragma unroll
                    for (int r = 0; r < 4; ++r) {
                        float v = acc[m][n][r] + bn;
                        v = fminf(fmaxf(v, -15.f), 15.f);
                        if (g == 0) {
                            tt[m][n][r] = __builtin_amdgcn_exp2f(v * LOG2E);
                        } else if (g == 1) {
                            float eg = __builtin_amdgcn_exp2f(v * LOG2E2);
                            float ei = tt[m][n][r];
                            float c = ei * (eg - 1.f) *
                                      __builtin_amdgcn_rcpf((1.f + ei) * (1.f + eg));
                            float z = c * c;
                            float tn = fmaf(z + 105.f, z, 945.f);
                            float td = fmaf(fmaf(15.f, z, 420.f), z, 945.f);
                            tt[m][n][r] = c * tn * __builtin_amdgcn_rcpf(td);
                        } else {
                            float eo = __builtin_amdgcn_exp2f(v * LOG2E);
                            tt[m][n][r] = tt[m][n][r] * eo *
                                          __builtin_amdgcn_rcpf(1.f + eo);
                        }
                    }
            }
        }
        __syncthreads();   // all waves done reading h_lds
#pragma unroll
        for (int n = 0; n < 2; ++n) {
            int col = wid * 32 + n * 16 + l15;
#pragma unroll
            for (int m = 0; m < 4; ++m)
#pragma unroll
                for (int r = 0; r < 4; ++r) {
                    int row = m * 16 + lq * 4 + r;
                    *(__bf16*)((char*)h_lds + ((row * 512 + col * 2) ^ ((row & 7) << 4))) =
                        (__bf16)tt[m][n][r];
                }
        }
        __syncthreads();
    }

    // ---- final GEMM: out = h @ W_fc^T + b_fc (N padded 63->64) ----
    {
        const int mt = wid & 3;          // row tile
        const int nb0 = (wid >> 2) * 2;  // col tiles nb0, nb0+1
        f32x4 o4[2];
#pragma unroll
        for (int n = 0; n < 2; ++n) o4[n] = (f32x4){0.f, 0.f, 0.f, 0.f};
#pragma unroll
        for (int kk = 0; kk < 8; ++kk) {
            int row = mt * 16 + l15;
            bf16_8 a = *(const bf16_8*)((const char*)h_lds +
                        ((row * 512 + kk * 64 + lq * 16) ^ ((row & 7) << 4)));
#pragma unroll
            for (int n = 0; n < 2; ++n) {
                bf16_8 b = *(const bf16_8*)(Bfc + (((nb0 + n) * 8 + kk) << 9) + lane * 8);
                o4[n] = __builtin_amdgcn_mfma_f32_16x16x32_bf16(a, b, o4[n], 0, 0, 0);
            }
        }
#pragma unroll
        for (int n = 0; n < 2; ++n) {
            int col = (nb0 + n) * 16 + l15;
            if (col < DIO) {
                float bn = b_fc[col];
#pragma unroll
                for (int r = 0; r < 4; ++r) {
                    int row = mt * 16 + lq * 4 + r;
                    out[(size_t)(row0 + row) * DIO + col] = o4[n][r] + bn;
                }
            }
        }
    }
}

extern "C" void kernel_launch(void* const* d_in, const int* in_sizes, int n_in,
                              void* d_out, int out_size, void* d_ws, size_t ws_size,
                              hipStream_t stream) {
    const float* inputs = (const float*)d_in[0];
    const float* W_in   = (const float*)d_in[1];
    const float* b_in   = (const float*)d_in[2];
    const float* W_ih   = (const float*)d_in[3];
    // d_in[4] = W_hh: unused (h_prev == 0 every step)
    const float* b_ih   = (const float*)d_in[5];
    const float* b_hh   = (const float*)d_in[6];
    const float* W_fc   = (const float*)d_in[7];
    const float* b_fc   = (const float*)d_in[8];

    unsigned short* Bg  = (unsigned short*)d_ws;
    float* bias         = (float*)((char*)d_ws + (size_t)NBGF * 2);
    unsigned short* Bin = (unsigned short*)((char*)bias + (size_t)NBIAS * 4);
    unsigned short* Bfc = Bin + NBINF;

    int total = NBGF + NBIAS + NBINF + NBFCF;
    prep_kernel<<<(total + 255) / 256, 256, 0, stream>>>(W_in, W_ih, b_ih, b_hh, W_fc,
                                                         Bg, bias, Bin, Bfc);
    rnn_fused<<<STEPS / BM, THREADS, 0, stream>>>(inputs, b_in, b_fc, Bg, bias, Bin, Bfc,
                                                  (float*)d_out);
}